// Round 6
// baseline (1443.193 us; speedup 1.0000x reference)
//
#include <hip/hip_runtime.h>

// Residual VQ, bit-exact replication of the numpy reference's fp32 rounding.
// B=16 S=2048 D=64 K=8 M=2048.
//
// Numerics contract (verified bit-exact, absmax 0.0):
//  - r2/c2: numpy pairwise_sum 8-accumulator order, no FMA contraction
//  - cross: numpy einsum baseline-SSE order: 4 chains (d mod 4), per 16-block
//           groups at offsets {12,8,4,0}+j, blocks ascending, hsum (L0+L1)+(L2+L3)
//  - t = fl(r2 - 2*cross) via fma(-2,cross,r2); d2 = fl(t + c2)
//  - argmin: first occurrence == u64-min over key {d2_bits(hi), m(lo)} (d2>0)
//
// R11 transport model (calibrated on R5-R10):
//  - scalar K$: ~5 cy/request, port shared per 4 CUs (hits pay too).
//  - VMEM: ~17 cy/instr/wave on the per-CU pipe, broadcast or not. R10 lesson:
//    a helper pipe with a hard per-row vmcnt(0) must stay at LOW utilization
//    (R10's 76% VMEM util -> ~800cy queue delay > lead -> stalls, 187us).
//  - LDS broadcast ds_read_b128: ~12 cy/instr/wave on the per-CU pipe.
//  - VALU demand (measured R9): ~1333 cy per CU-row-window (4 waves/SIMD).
// R11 split: SMEM d0..31 (2 dwordx16 + c2 = 3 req, P/Q ping-pong s[32:95]);
// LDS d32..47 + d52..63 restaged contiguously ([256][28], 112B stride, 28KB)
// = 7 ds_read_b128 -> v[96:123]; VMEM d48..51 = ONE broadcast dwordx4/row
// -> v[124:127] (16% pipe util), consumed LAST in the einsum (b48 d0=48
// group) so vmcnt(0) lands after 15/16 groups (~1.3-row lead).
// Budget/window: LDS 1344 ~ VALU 1333 > scalar 960 >> VMEM 272.
// FP op sequence operand-identical -> bit-exact preserved.

#define BB 16
#define SS 2048
#define DD 64
#define KK 8
#define MM 2048
#define NPTS (BB * SS)      // 32768
#define QSIZE (NPTS * DD)   // 2097152
#define NCHUNK 8
#define WPB 8               // waves per block (all same chunk)
#define PPB 512             // points per block
#define MCHUNK (MM / NCHUNK)  // 256 rows per chunk

// ---- prep: c2[k][m] (numpy pairwise) + key init ----
__global__ __launch_bounds__(256) void rvq_prep(const float* __restrict__ cb,
                                                float* __restrict__ c2,
                                                unsigned long long* __restrict__ keys) {
#pragma clang fp contract(off)
    int tid = blockIdx.x * 256 + threadIdx.x;  // 0 .. K*M-1 = 16383
    const float* row = cb + (size_t)tid * DD;
    float r[8];
#pragma unroll
    for (int j = 0; j < 8; ++j) { float v = row[j]; r[j] = v * v; }
#pragma unroll
    for (int i = 8; i < DD; i += 8) {
#pragma unroll
        for (int j = 0; j < 8; ++j) { float v = row[i + j]; float t = v * v; r[j] += t; }
    }
    c2[tid] = ((r[0] + r[1]) + (r[2] + r[3])) + ((r[4] + r[5]) + (r[6] + r[7]));
    keys[tid] = ~0ULL;                 // NPTS = 2 * K*M
    keys[tid + KK * MM] = ~0ULL;
}

// r2 chain block for k-th 8-float group (bases A=16+8k, etc.)
#define R2K(A, B, C, E) \
    "v_pk_mul_f32 v[92:93], v[" A "], v[" A "]\n\t" \
    "v_pk_add_f32 v[80:81], v[80:81], v[92:93]\n\t" \
    "v_pk_mul_f32 v[92:93], v[" B "], v[" B "]\n\t" \
    "v_pk_add_f32 v[82:83], v[82:83], v[92:93]\n\t" \
    "v_pk_mul_f32 v[92:93], v[" C "], v[" C "]\n\t" \
    "v_pk_add_f32 v[84:85], v[84:85], v[92:93]\n\t" \
    "v_pk_mul_f32 v[92:93], v[" E "], v[" E "]\n\t" \
    "v_pk_add_f32 v[86:87], v[86:87], v[92:93]\n\t"

// einsum group, codebook from SGPR pairs
#define GRP(SA, SB, VA, VB) \
    "v_pk_mul_f32 v[84:85], s[" SA "], v[" VA "]\n\t" \
    "v_pk_mul_f32 v[86:87], s[" SB "], v[" VB "]\n\t" \
    "v_pk_add_f32 v[80:81], v[80:81], v[84:85]\n\t" \
    "v_pk_add_f32 v[82:83], v[82:83], v[86:87]\n\t"

// einsum group, codebook from VGPR pairs (LDS/VMEM-transported)
#define GRPL(CA, CB, VA, VB) \
    "v_pk_mul_f32 v[84:85], v[" CA "], v[" VA "]\n\t" \
    "v_pk_mul_f32 v[86:87], v[" CB "], v[" VB "]\n\t" \
    "v_pk_add_f32 v[80:81], v[80:81], v[84:85]\n\t" \
    "v_pk_add_f32 v[82:83], v[82:83], v[86:87]\n\t"

// issue SMEM (d0..31, 128B = 2 dwordx16) + c2 into buffer; clamped ptr s29
#define SMEMLD(BA, BB, C2D) \
    "s_min_u32 s30, s29, 0xff00\n\t" \
    "s_load_dwordx16 s[" BA "], %[cb], s30\n\t" \
    "s_add_u32 s25, s30, 64\n\t" \
    "s_load_dwordx16 s[" BB "], %[cb], s25\n\t" \
    "s_lshr_b32 s25, s30, 6\n\t" \
    "s_load_dword " C2D ", %[c2], s25\n\t" \
    "s_add_u32 s29, s29, 256\n\t"

// issue LDS row (d32..47,d52..63 = 112B = 7 b128) -> v[96:123]; advance v94
#define DSLD7 \
    "ds_read_b128 v[96:99],   v94\n\t" \
    "ds_read_b128 v[100:103], v94 offset:16\n\t" \
    "ds_read_b128 v[104:107], v94 offset:32\n\t" \
    "ds_read_b128 v[108:111], v94 offset:48\n\t" \
    "ds_read_b128 v[112:115], v94 offset:64\n\t" \
    "ds_read_b128 v[116:119], v94 offset:80\n\t" \
    "ds_read_b128 v[120:123], v94 offset:96\n\t" \
    "v_add_u32 v94, 0x70, v94\n\t" \
    "v_min_u32 v94, %[lc], v94\n\t"

// einsum b0+b16 from SMEM P buffer s[32:63]
#define EINSM_P \
    "v_pk_mul_f32 v[80:81], s[44:45], v[28:29]\n\t" \
    "v_pk_mul_f32 v[82:83], s[46:47], v[30:31]\n\t" \
    GRP("40:41","42:43","24:25","26:27") \
    GRP("36:37","38:39","20:21","22:23") \
    GRP("32:33","34:35","16:17","18:19") \
    GRP("60:61","62:63","44:45","46:47") \
    GRP("56:57","58:59","40:41","42:43") \
    GRP("52:53","54:55","36:37","38:39") \
    GRP("48:49","50:51","32:33","34:35")

// einsum b0+b16 from SMEM Q buffer s[64:95]
#define EINSM_Q \
    "v_pk_mul_f32 v[80:81], s[76:77], v[28:29]\n\t" \
    "v_pk_mul_f32 v[82:83], s[78:79], v[30:31]\n\t" \
    GRP("72:73","74:75","24:25","26:27") \
    GRP("68:69","70:71","20:21","22:23") \
    GRP("64:65","66:67","16:17","18:19") \
    GRP("92:93","94:95","44:45","46:47") \
    GRP("88:89","90:91","40:41","42:43") \
    GRP("84:85","86:87","36:37","38:39") \
    GRP("80:81","82:83","32:33","34:35")

// einsum b32 (LDS d32..47) + b48 (LDS d60,56,52; VMEM d48 last).
// Next-row VMEM load issued right after its operands' final consumers;
// vmcnt(0) lands after 15/16 groups -> ~1.3-row natural lead.
#define EIN_TAIL \
    GRPL("108:109","110:111","60:61","62:63") \
    GRPL("104:105","106:107","56:57","58:59") \
    GRPL("100:101","102:103","52:53","54:55") \
    GRPL("96:97","98:99","48:49","50:51") \
    GRPL("120:121","122:123","76:77","78:79") \
    GRPL("116:117","118:119","72:73","74:75") \
    GRPL("112:113","114:115","68:69","70:71") \
    "s_waitcnt vmcnt(0)\n\t" \
    "v_pk_mul_f32 v[84:85], v[124:125], v[64:65]\n\t" \
    "v_pk_mul_f32 v[86:87], v[126:127], v[66:67]\n\t" \
    "global_load_dwordx4 v[124:127], v95, %[cb] offset:192\n\t" \
    "v_add_u32 v95, 0x100, v95\n\t" \
    "v_min_u32 v95, 0xff00, v95\n\t" \
    "v_pk_add_f32 v[80:81], v[80:81], v[84:85]\n\t" \
    "v_pk_add_f32 v[82:83], v[82:83], v[86:87]\n\t"

// hsum, d2, argmin update; C2S = SGPR holding c2 of this row
#define FINX(C2S) \
    "v_add_f32 v92, v80, v81\n\t" \
    "v_add_f32 v93, v82, v83\n\t" \
    "v_add_f32 v92, v92, v93\n\t" \
    "v_fma_f32 v92, v92, -2.0, v88\n\t" \
    "v_add_f32 v92, " C2S ", v92\n\t" \
    "v_cmp_lt_f32 vcc, v92, v89\n\t" \
    "v_cndmask_b32 v89, v89, v92, vcc\n\t" \
    "v_cndmask_b32 v90, v90, v91, vcc\n\t" \
    "v_add_u32 v91, 1, v91\n\t"

// ---- main: per-chunk argmin, atomicMin-combined ----
// grid = 512 blocks x 512 threads (8 waves). Block b: chunk = b & 7,
// point-group = b >> 3. 2 blocks/CU, 4 waves/SIMD, 28KB LDS/block.
__global__ __launch_bounds__(512, 4) void rvq_main(const float* __restrict__ res_in,
                                                   const float* __restrict__ cbk,  // (M,D)
                                                   const float* __restrict__ c2k,  // (M,)
                                                   unsigned long long* __restrict__ keys) {
#pragma clang fp contract(off)
    const int tid = threadIdx.x;
    const int lane = tid & 63;
    const int wv = __builtin_amdgcn_readfirstlane(tid >> 6);  // 0..7
    const int ch = blockIdx.x & (NCHUNK - 1);
    const int bp = blockIdx.x >> 3;
    const int point = bp * PPB + wv * 64 + lane;

    const int m0 = ch * MCHUNK;
    const float* cbw = cbk + (size_t)m0 * DD;   // this block's chunk base
    const float* c2w = c2k + m0;
    const unsigned long long ra = (unsigned long long)(res_in + (size_t)point * DD);

    // ---- stage [d32..47, d52..63] of the chunk into LDS: [256 rows][28 f],
    //      112B stride (16B-aligned for all 7 b128 offsets) ----
    __shared__ __align__(16) float lds_cb[MCHUNK * 28];   // 28 KB
    for (int i = tid; i < MCHUNK * 7; i += PPB) {         // 1792 float4s
        const int row = i / 7;
        const int j = i - row * 7;
        const int src = (j < 4) ? (32 + 4 * j) : (36 + 4 * j);  // d32..47 | d52..63
        *(float4*)&lds_cb[row * 28 + j * 4] = *(const float4*)(cbw + row * DD + src);
    }
    __syncthreads();
    const unsigned ldsbase = (unsigned)(unsigned long long)(void*)&lds_cb[0];
    const unsigned ldsclamp = ldsbase + (MCHUNK - 1) * 112;

    float best;
    int bidx;
    asm volatile(
        // ---- residual: 64 floats -> v[16:79]; v95 pre-init for V prime ----
        "v_mov_b32 v95, 0\n\t"
        "global_load_dwordx4 v[16:19], %[ra], off\n\t"
        "global_load_dwordx4 v[20:23], %[ra], off offset:16\n\t"
        "global_load_dwordx4 v[24:27], %[ra], off offset:32\n\t"
        "global_load_dwordx4 v[28:31], %[ra], off offset:48\n\t"
        "global_load_dwordx4 v[32:35], %[ra], off offset:64\n\t"
        "global_load_dwordx4 v[36:39], %[ra], off offset:80\n\t"
        "global_load_dwordx4 v[40:43], %[ra], off offset:96\n\t"
        "global_load_dwordx4 v[44:47], %[ra], off offset:112\n\t"
        "global_load_dwordx4 v[48:51], %[ra], off offset:128\n\t"
        "global_load_dwordx4 v[52:55], %[ra], off offset:144\n\t"
        "global_load_dwordx4 v[56:59], %[ra], off offset:160\n\t"
        "global_load_dwordx4 v[60:63], %[ra], off offset:176\n\t"
        "global_load_dwordx4 v[64:67], %[ra], off offset:192\n\t"
        "global_load_dwordx4 v[68:71], %[ra], off offset:208\n\t"
        "global_load_dwordx4 v[72:75], %[ra], off offset:224\n\t"
        "global_load_dwordx4 v[76:79], %[ra], off offset:240\n\t"
        "s_waitcnt vmcnt(0)\n\t"
        // ---- prime VMEM row 0 (d48..51; latency covered by r2 compute) ----
        "global_load_dwordx4 v[124:127], v95, %[cb] offset:192\n\t"
        "v_mov_b32 v95, 0x100\n\t"
        // ---- r2, numpy pairwise 8-acc order; accs in v[80:87] ----
        "v_pk_mul_f32 v[80:81], v[16:17], v[16:17]\n\t"
        "v_pk_mul_f32 v[82:83], v[18:19], v[18:19]\n\t"
        "v_pk_mul_f32 v[84:85], v[20:21], v[20:21]\n\t"
        "v_pk_mul_f32 v[86:87], v[22:23], v[22:23]\n\t"
        R2K("24:25", "26:27", "28:29", "30:31")
        R2K("32:33", "34:35", "36:37", "38:39")
        R2K("40:41", "42:43", "44:45", "46:47")
        R2K("48:49", "50:51", "52:53", "54:55")
        R2K("56:57", "58:59", "60:61", "62:63")
        R2K("64:65", "66:67", "68:69", "70:71")
        R2K("72:73", "74:75", "76:77", "78:79")
        "v_add_f32 v92, v80, v81\n\t"
        "v_add_f32 v93, v82, v83\n\t"
        "v_add_f32 v92, v92, v93\n\t"
        "v_add_f32 v93, v84, v85\n\t"
        "v_add_f32 v88, v86, v87\n\t"
        "v_add_f32 v93, v93, v88\n\t"
        "v_add_f32 v88, v92, v93\n\t"          // r2 -> v88
        // ---- init ----
        "v_mov_b32 v89, 0x7f800000\n\t"        // best = +inf
        "v_mov_b32 v90, 0\n\t"                 // bidx = 0
        "v_mov_b32 v91, %[m0]\n\t"             // current m
        "v_mov_b32 v94, %[lb]\n\t"             // LDS read ptr (row 0)
        "s_mov_b32 s29, 0\n\t"                 // SMEM prefetch byte offset
        SMEMLD("32:47", "48:63", "s26")        // P(0); s29 -> 256
        DSLD7                                  // ds(0); v94 -> row 1
        "s_mov_b32 s24, 0\n\t"                 // row-pair counter
        "Ltop_%=:\n\t"
        // ---- row r (even, buffer P): in flight on entry: P(r), ds(r), V(r) ----
        "s_waitcnt lgkmcnt(0)\n\t"
        SMEMLD("64:79", "80:95", "s27")        // issue Q(r+1), full-einsum lead
        EINSM_P
        EIN_TAIL                               // b32+b48; issues V(r+1) inside
        DSLD7                                  // issue ds(r+1)
        FINX("s26")
        // ---- row r+1 (odd, buffer Q) ----
        "s_waitcnt lgkmcnt(0)\n\t"
        SMEMLD("32:47", "48:63", "s26")        // issue P(r+2)
        EINSM_Q
        EIN_TAIL                               // issues V(r+2)
        DSLD7                                  // issue ds(r+2)
        FINX("s27")
        "s_add_u32 s24, s24, 1\n\t"
        "s_cmp_lg_u32 s24, 128\n\t"
        "s_cbranch_scc1 Ltop_%=\n\t"
        "s_waitcnt vmcnt(0) lgkmcnt(0)\n\t"    // drain trailing prefetches
        "v_mov_b32 %[ob], v89\n\t"
        "v_mov_b32 %[oi], v90\n\t"
        : [ob] "=v"(best), [oi] "=v"(bidx)
        : [ra] "v"(ra), [cb] "s"(cbw), [c2] "s"(c2w), [m0] "s"(m0),
          [lb] "s"(ldsbase), [lc] "s"(ldsclamp)
        : "vcc", "scc",
          "s24","s25","s26","s27","s29","s30",
          "s32","s33","s34","s35","s36","s37","s38","s39",
          "s40","s41","s42","s43","s44","s45","s46","s47","s48","s49","s50","s51",
          "s52","s53","s54","s55","s56","s57","s58","s59","s60","s61","s62","s63",
          "s64","s65","s66","s67","s68","s69","s70","s71","s72","s73","s74","s75",
          "s76","s77","s78","s79","s80","s81","s82","s83","s84","s85","s86","s87",
          "s88","s89","s90","s91","s92","s93","s94","s95",
          "v16","v17","v18","v19","v20","v21","v22","v23","v24","v25","v26","v27",
          "v28","v29","v30","v31","v32","v33","v34","v35","v36","v37","v38","v39",
          "v40","v41","v42","v43","v44","v45","v46","v47","v48","v49","v50","v51",
          "v52","v53","v54","v55","v56","v57","v58","v59","v60","v61","v62","v63",
          "v64","v65","v66","v67","v68","v69","v70","v71","v72","v73","v74","v75",
          "v76","v77","v78","v79","v80","v81","v82","v83","v84","v85","v86","v87",
          "v88","v89","v90","v91","v92","v93","v94","v95","v96","v97","v98","v99",
          "v100","v101","v102","v103","v104","v105","v106","v107","v108","v109",
          "v110","v111","v112","v113","v114","v115","v116","v117","v118","v119",
          "v120","v121","v122","v123","v124","v125","v126","v127");

    // ---- cross-chunk combine: u64-min over {d2_bits, m}. d2 > 0 always, so
    // u64 order == (d2, then m) == reference first-occurrence semantics.
    unsigned long long key =
        ((unsigned long long)__float_as_uint(best) << 32) | (unsigned int)bidx;
    atomicMin(&keys[point], key);
}

// ---- update: unpack winner, write idx, residual update, key reset ----
// grid = QSIZE/256. Block covers 4 points x 64 dims.
__global__ __launch_bounds__(256) void rvq_update(const float* __restrict__ res_in,
                                                  float* __restrict__ res_out,
                                                  const float* __restrict__ x,
                                                  const float* __restrict__ cbk,  // (M,D)
                                                  unsigned long long* __restrict__ keys,
                                                  float* __restrict__ idx_out,
                                                  int last) {
#pragma clang fp contract(off)
    __shared__ unsigned long long sk[4];
    const int tid = threadIdx.x;
    const int e = blockIdx.x * 256 + tid;
    const int p0 = blockIdx.x * 4;
    if (tid < 4) {
        unsigned long long k = keys[p0 + tid];
        sk[tid] = k;
        keys[p0 + tid] = ~0ULL;                       // reset for next step
        idx_out[p0 + tid] = (float)(unsigned int)k;   // exact for m < 2^24
    }
    __syncthreads();
    const int pi = tid >> 6;
    const int d = tid & 63;
    const int m = (int)(unsigned int)sk[pi];
    const float r = res_in[e] - cbk[(size_t)m * DD + d];  // exact fp32 sub
    if (last) res_out[e] = x[e] - r;   // quant = fl(x - fl(res - cb)); alias-safe
    else      res_out[e] = r;
}

extern "C" void kernel_launch(void* const* d_in, const int* in_sizes, int n_in,
                              void* d_out, int out_size, void* d_ws, size_t ws_size,
                              hipStream_t stream) {
    const float* x  = (const float*)d_in[0];
    const float* cb = (const float*)d_in[1];

    float* out = (float*)d_out;
    float* quant = out;                 // QSIZE floats
    float* idx_out = out + QSIZE;       // K*NPTS floats (indices as float)

    float* c2   = (float*)d_ws;                       // K*M floats (64 KB)
    float* res1 = c2 + (size_t)KK * MM;               // NPTS*D floats (8 MB)
    unsigned long long* keys =
        (unsigned long long*)(res1 + (size_t)QSIZE);  // NPTS u64 (256 KB)
    float* R[2] = { quant, res1 };                    // ping-pong residual

    rvq_prep<<<(KK * MM) / 256, 256, 0, stream>>>(cb, c2, keys);

    for (int k = 0; k < KK; ++k) {
        const float* rin = (k == 0) ? x : R[(k - 1) & 1];
        const int last = (k == KK - 1);
        float* rout = last ? quant : R[k & 1];
        rvq_main<<<(NPTS / PPB) * NCHUNK, PPB, 0, stream>>>(
            rin,
            cb + (size_t)k * MM * DD,
            c2 + (size_t)k * MM,
            keys);
        rvq_update<<<QSIZE / 256, 256, 0, stream>>>(
            rin, rout, x,
            cb + (size_t)k * MM * DD,
            keys,
            idx_out + (size_t)k * NPTS,
            last);
    }
}

// Round 9
// 1309.303 us; speedup vs baseline: 1.1023x; 1.1023x over previous
//
#include <hip/hip_runtime.h>

// Residual VQ, bit-exact replication of the numpy reference's fp32 rounding.
// B=16 S=2048 D=64 K=8 M=2048.
//
// Numerics contract (verified bit-exact, absmax 0.0):
//  - r2/c2: numpy pairwise_sum 8-accumulator order, no FMA contraction
//  - cross: numpy einsum baseline-SSE order: 4 chains (d mod 4), per 16-block
//           groups at offsets {12,8,4,0}+j, blocks ascending, hsum (L0+L1)+(L2+L3)
//  - t = fl(r2 - 2*cross) via fma(-2,cross,r2); d2 = fl(t + c2)
//  - argmin: first occurrence == u64-min over key {d2_bits(hi), m(lo)} (d2>0)
//
// R15 (asymmetric pair, 3rd attempt). R12/R13 compile fails: SGPR demand
// (clobber+operand) >= 90 is unallocatable; <= 74 proven OK. Fix: prep packs
// per-(k,chunk) [256 rows x 64f | 256 c2 floats] so the hot loop has ONE
// scalar pointer. Clobbers s12-s95 (84) + 2 operand SGPRs; s0-s11 free.
// All s_load forms are (sbase, soffset-reg) or (sbase, imm) only.
// R9 accounting: LDS pipe 94% util (16 b128/pair) is the binder. R15 split:
//  A rows (even): d0..47 SMEM s[32:79] (3 x16), d48..63 LDS (4 b128 v[96:111])
//  B rows (odd):  d0..15 s[16:31], d16..31 s[80:95] (2 x16),
//                 d32..63 LDS (8 b128 v[96:127])
//  c2 per PAIR: one s_load_dwordx2 s[12:13] at loop bottom (both consumers done).
// Per pair-window (2666cy VALU): LDS 2304 (86%), scalar 1920 (72%), VMEM 0.
// FP op sequence operand-identical -> bit-exact. Combine/update = R9's.

#define BB 16
#define SS 2048
#define DD 64
#define KK 8
#define MM 2048
#define NPTS (BB * SS)      // 32768
#define QSIZE (NPTS * DD)   // 2097152
#define NCHUNK 8
#define WPB 8               // waves per block (all same chunk)
#define PPB 512             // points per block
#define MCHUNK (MM / NCHUNK)  // 256 rows per chunk = 128 pairs
#define PACKF 16640         // floats per packed chunk block: 16384 rows + 256 c2

// ---- prep: pack rows + c2 per (k,chunk); init keys ----
// grid = 64 blocks (one per (k,chunk)) x 256 threads.
__global__ __launch_bounds__(256) void rvq_prep(const float* __restrict__ cb,
                                                float* __restrict__ pack,
                                                unsigned long long* __restrict__ keys) {
#pragma clang fp contract(off)
    const int b = blockIdx.x;          // k = b>>3, chunk = b&7
    const int tid = threadIdx.x;
    const float* src = cb + (size_t)b * 16384;   // chunk rows are contiguous
    float* dst = pack + (size_t)b * PACKF;
    // copy rows region (64KB), coalesced float4
    for (int i = tid; i < 4096; i += 256)
        *(float4*)&dst[i * 4] = *(const float4*)&src[i * 4];
    // c2 for local row tid (numpy pairwise 8-acc)
    const float* row = src + (size_t)tid * DD;
    float r[8];
#pragma unroll
    for (int j = 0; j < 8; ++j) { float v = row[j]; r[j] = v * v; }
#pragma unroll
    for (int i = 8; i < DD; i += 8) {
#pragma unroll
        for (int j = 0; j < 8; ++j) { float v = row[i + j]; float t = v * v; r[j] += t; }
    }
    dst[16384 + tid] = ((r[0] + r[1]) + (r[2] + r[3])) + ((r[4] + r[5]) + (r[6] + r[7]));
    keys[b * 512 + tid] = ~0ULL;
    keys[b * 512 + 256 + tid] = ~0ULL;
}

// r2 chain block for k-th 8-float group (bases A=16+8k, etc.)
#define R2K(A, B, C, E) \
    "v_pk_mul_f32 v[92:93], v[" A "], v[" A "]\n\t" \
    "v_pk_add_f32 v[80:81], v[80:81], v[92:93]\n\t" \
    "v_pk_mul_f32 v[92:93], v[" B "], v[" B "]\n\t" \
    "v_pk_add_f32 v[82:83], v[82:83], v[92:93]\n\t" \
    "v_pk_mul_f32 v[92:93], v[" C "], v[" C "]\n\t" \
    "v_pk_add_f32 v[84:85], v[84:85], v[92:93]\n\t" \
    "v_pk_mul_f32 v[92:93], v[" E "], v[" E "]\n\t" \
    "v_pk_add_f32 v[86:87], v[86:87], v[92:93]\n\t"

// einsum group, codebook from SGPR pairs
#define GRP(SA, SB, VA, VB) \
    "v_pk_mul_f32 v[84:85], s[" SA "], v[" VA "]\n\t" \
    "v_pk_mul_f32 v[86:87], s[" SB "], v[" VB "]\n\t" \
    "v_pk_add_f32 v[80:81], v[80:81], v[84:85]\n\t" \
    "v_pk_add_f32 v[82:83], v[82:83], v[86:87]\n\t"

// einsum group, codebook from VGPR pairs (LDS-transported)
#define GRPL(CA, CB, VA, VB) \
    "v_pk_mul_f32 v[84:85], v[" CA "], v[" VA "]\n\t" \
    "v_pk_mul_f32 v[86:87], v[" CB "], v[" VB "]\n\t" \
    "v_pk_add_f32 v[80:81], v[80:81], v[84:85]\n\t" \
    "v_pk_add_f32 v[82:83], v[82:83], v[86:87]\n\t"

// A-top: issue SMEM B (current pair row 2q+1, d0..31); temp s15
#define SMEM_B_ISSUE \
    "s_add_u32 s15, s14, 0x100\n\t" \
    "s_load_dwordx16 s[16:31], %[pb], s15\n\t" \
    "s_add_u32 s15, s15, 0x40\n\t" \
    "s_load_dwordx16 s[80:95], %[pb], s15\n\t"

// B-top: issue SMEM A (next pair, d0..47); leaves s15 = clamped_base + 0x80
#define SMEM_A_NEXT \
    "s_add_u32 s15, s14, 0x200\n\t" \
    "s_min_u32 s15, s15, 0xfe00\n\t" \
    "s_load_dwordx16 s[32:47], %[pb], s15\n\t" \
    "s_add_u32 s15, s15, 0x40\n\t" \
    "s_load_dwordx16 s[48:63], %[pb], s15\n\t" \
    "s_add_u32 s15, s15, 0x40\n\t" \
    "s_load_dwordx16 s[64:79], %[pb], s15\n\t"

// loop bottom: c2 pair of next pair -> s[12:13] (both FINX consumers done).
// s15 = clamped_base + 0x80; c2 byte = 0x10000 + clamped_base>>6
//      = (s15>>6) + (0x10000 - 2).
#define C2_NEXT \
    "s_lshr_b32 s15, s15, 6\n\t" \
    "s_add_u32 s15, s15, 0xfffe\n\t" \
    "s_load_dwordx2 s[12:13], %[pb], s15\n\t"

// einsum b0+b16+b32 from A SMEM buffer s[32:79] (d -> s[32+d])
#define EINSM_A \
    "v_pk_mul_f32 v[80:81], s[44:45], v[28:29]\n\t" \
    "v_pk_mul_f32 v[82:83], s[46:47], v[30:31]\n\t" \
    GRP("40:41","42:43","24:25","26:27") \
    GRP("36:37","38:39","20:21","22:23") \
    GRP("32:33","34:35","16:17","18:19") \
    GRP("60:61","62:63","44:45","46:47") \
    GRP("56:57","58:59","40:41","42:43") \
    GRP("52:53","54:55","36:37","38:39") \
    GRP("48:49","50:51","32:33","34:35") \
    GRP("76:77","78:79","60:61","62:63") \
    GRP("72:73","74:75","56:57","58:59") \
    GRP("68:69","70:71","52:53","54:55") \
    GRP("64:65","66:67","48:49","50:51")

// A b48 from LDS v[96:111] (d = 48+i -> v[96+i])
#define TAIL_A \
    GRPL("108:109","110:111","76:77","78:79") \
    GRPL("104:105","106:107","72:73","74:75") \
    GRPL("100:101","102:103","68:69","70:71") \
    GRPL("96:97","98:99","64:65","66:67")

// issue ds_B (current pair, d32..63 -> v[96:127]); pair base v94 + 64..176
#define DS_B \
    "ds_read_b128 v[96:99],   v94 offset:64\n\t" \
    "ds_read_b128 v[100:103], v94 offset:80\n\t" \
    "ds_read_b128 v[104:107], v94 offset:96\n\t" \
    "ds_read_b128 v[108:111], v94 offset:112\n\t" \
    "ds_read_b128 v[112:115], v94 offset:128\n\t" \
    "ds_read_b128 v[116:119], v94 offset:144\n\t" \
    "ds_read_b128 v[120:123], v94 offset:160\n\t" \
    "ds_read_b128 v[124:127], v94 offset:176\n\t"

// einsum b0+b16 from B SMEM buffers s[16:31] (d0..15) + s[80:95] (d16..31)
#define EINSM_B \
    "v_pk_mul_f32 v[80:81], s[28:29], v[28:29]\n\t" \
    "v_pk_mul_f32 v[82:83], s[30:31], v[30:31]\n\t" \
    GRP("24:25","26:27","24:25","26:27") \
    GRP("20:21","22:23","20:21","22:23") \
    GRP("16:17","18:19","16:17","18:19") \
    GRP("92:93","94:95","44:45","46:47") \
    GRP("88:89","90:91","40:41","42:43") \
    GRP("84:85","86:87","36:37","38:39") \
    GRP("80:81","82:83","32:33","34:35")

// B b32 from LDS v[96:111] (d = 32+i -> v[96+i]); then reissue ds_A(next pair)
// into the just-freed v[96:111] (offsets 192..240 = next pair's A region)
#define B_B32_THEN_DSA \
    GRPL("108:109","110:111","60:61","62:63") \
    GRPL("104:105","106:107","56:57","58:59") \
    GRPL("100:101","102:103","52:53","54:55") \
    GRPL("96:97","98:99","48:49","50:51") \
    "ds_read_b128 v[96:99],   v94 offset:192\n\t" \
    "ds_read_b128 v[100:103], v94 offset:208\n\t" \
    "ds_read_b128 v[104:107], v94 offset:224\n\t" \
    "ds_read_b128 v[108:111], v94 offset:240\n\t"

// B b48 from LDS v[112:127] (d = 48+i -> v[112+i]); advance pair base
#define B_B48 \
    GRPL("124:125","126:127","76:77","78:79") \
    GRPL("120:121","122:123","72:73","74:75") \
    GRPL("116:117","118:119","68:69","70:71") \
    GRPL("112:113","114:115","64:65","66:67") \
    "v_add_u32 v94, 0xc0, v94\n\t"

// hsum, d2, argmin update; C2S = SGPR holding c2 of this row
#define FINX(C2S) \
    "v_add_f32 v92, v80, v81\n\t" \
    "v_add_f32 v93, v82, v83\n\t" \
    "v_add_f32 v92, v92, v93\n\t" \
    "v_fma_f32 v92, v92, -2.0, v88\n\t" \
    "v_add_f32 v92, " C2S ", v92\n\t" \
    "v_cmp_lt_f32 vcc, v92, v89\n\t" \
    "v_cndmask_b32 v89, v89, v92, vcc\n\t" \
    "v_cndmask_b32 v90, v90, v91, vcc\n\t" \
    "v_add_u32 v91, 1, v91\n\t"

// ---- main: per-chunk argmin, atomicMin-combined ----
// grid = 512 blocks x 512 threads (8 waves). Block b: chunk = b & 7,
// point-group = b >> 3. 2 blocks/CU, 4 waves/SIMD, ~24.8KB LDS/block.
__global__ __launch_bounds__(512, 4) void rvq_main(const float* __restrict__ res_in,
                                                   const float* __restrict__ packk, // per-k pack
                                                   unsigned long long* __restrict__ keys) {
#pragma clang fp contract(off)
    const int tid = threadIdx.x;
    const int lane = tid & 63;
    const int wv = __builtin_amdgcn_readfirstlane(tid >> 6);  // 0..7
    const int ch = blockIdx.x & (NCHUNK - 1);
    const int bp = blockIdx.x >> 3;
    const int point = bp * PPB + wv * 64 + lane;

    const int m0 = ch * MCHUNK;
    const float* pbw = packk + (size_t)ch * PACKF;  // [rows 16384f | c2 256f]
    const unsigned long long ra = (unsigned long long)(res_in + (size_t)point * DD);

    // ---- stage LDS: per pair q (rows 2q,2q+1): [A d48..63 (16f)][B d32..63 (32f)]
    //      = 48 floats, 192B stride; + 1 pad pair for the tail prefetch ----
    __shared__ __align__(16) float lds_cb[128 * 48 + 48];   // 24768 B
    for (int i = tid; i < 128 * 12; i += PPB) {              // 1536 float4s
        const int q = i / 12;
        const int j = i - q * 12;
        const int row = 2 * q + (j >= 4);
        const int d = (j < 4) ? (48 + 4 * j) : (16 + 4 * j); // A: d48+4j | B: d32+4(j-4)
        *(float4*)&lds_cb[q * 48 + j * 4] = *(const float4*)(pbw + row * DD + d);
    }
    __syncthreads();
    const unsigned ldsbase = (unsigned)(unsigned long long)(void*)&lds_cb[0];

    float best;
    int bidx;
    asm volatile(
        // ---- residual: 64 floats -> v[16:79] ----
        "global_load_dwordx4 v[16:19], %[ra], off\n\t"
        "global_load_dwordx4 v[20:23], %[ra], off offset:16\n\t"
        "global_load_dwordx4 v[24:27], %[ra], off offset:32\n\t"
        "global_load_dwordx4 v[28:31], %[ra], off offset:48\n\t"
        "global_load_dwordx4 v[32:35], %[ra], off offset:64\n\t"
        "global_load_dwordx4 v[36:39], %[ra], off offset:80\n\t"
        "global_load_dwordx4 v[40:43], %[ra], off offset:96\n\t"
        "global_load_dwordx4 v[44:47], %[ra], off offset:112\n\t"
        "global_load_dwordx4 v[48:51], %[ra], off offset:128\n\t"
        "global_load_dwordx4 v[52:55], %[ra], off offset:144\n\t"
        "global_load_dwordx4 v[56:59], %[ra], off offset:160\n\t"
        "global_load_dwordx4 v[60:63], %[ra], off offset:176\n\t"
        "global_load_dwordx4 v[64:67], %[ra], off offset:192\n\t"
        "global_load_dwordx4 v[68:71], %[ra], off offset:208\n\t"
        "global_load_dwordx4 v[72:75], %[ra], off offset:224\n\t"
        "global_load_dwordx4 v[76:79], %[ra], off offset:240\n\t"
        "s_waitcnt vmcnt(0)\n\t"
        // ---- r2, numpy pairwise 8-acc order; accs in v[80:87] ----
        "v_pk_mul_f32 v[80:81], v[16:17], v[16:17]\n\t"
        "v_pk_mul_f32 v[82:83], v[18:19], v[18:19]\n\t"
        "v_pk_mul_f32 v[84:85], v[20:21], v[20:21]\n\t"
        "v_pk_mul_f32 v[86:87], v[22:23], v[22:23]\n\t"
        R2K("24:25", "26:27", "28:29", "30:31")
        R2K("32:33", "34:35", "36:37", "38:39")
        R2K("40:41", "42:43", "44:45", "46:47")
        R2K("48:49", "50:51", "52:53", "54:55")
        R2K("56:57", "58:59", "60:61", "62:63")
        R2K("64:65", "66:67", "68:69", "70:71")
        R2K("72:73", "74:75", "76:77", "78:79")
        "v_add_f32 v92, v80, v81\n\t"
        "v_add_f32 v93, v82, v83\n\t"
        "v_add_f32 v92, v92, v93\n\t"
        "v_add_f32 v93, v84, v85\n\t"
        "v_add_f32 v88, v86, v87\n\t"
        "v_add_f32 v93, v93, v88\n\t"
        "v_add_f32 v88, v92, v93\n\t"          // r2 -> v88
        // ---- init ----
        "v_mov_b32 v89, 0x7f800000\n\t"        // best = +inf
        "v_mov_b32 v90, 0\n\t"                 // bidx = 0
        "v_mov_b32 v91, %[m0]\n\t"             // current m
        "v_mov_b32 v94, %[lb]\n\t"             // LDS pair base (pair 0)
        "s_mov_b32 s14, 0\n\t"                 // pair byte base (512/pair)
        // ---- prime: SMEM A(0) + c2 pair(0) + ds_A(0) ----
        "s_load_dwordx16 s[32:47], %[pb], 0x0\n\t"
        "s_load_dwordx16 s[48:63], %[pb], 0x40\n\t"
        "s_load_dwordx16 s[64:79], %[pb], 0x80\n\t"
        "s_load_dwordx2 s[12:13], %[pb], 0x10000\n\t"
        "ds_read_b128 v[96:99],   v94\n\t"
        "ds_read_b128 v[100:103], v94 offset:16\n\t"
        "ds_read_b128 v[104:107], v94 offset:32\n\t"
        "ds_read_b128 v[108:111], v94 offset:48\n\t"
        "Ltop_%=:\n\t"
        // ---- row A (even): in flight on entry: SMEM A, c2 pair, ds_A ----
        "s_waitcnt lgkmcnt(0)\n\t"
        SMEM_B_ISSUE                           // full-phase lead for B's SMEM
        EINSM_A
        TAIL_A                                 // consumes v[96:111]
        DS_B                                   // issue ds_B -> v[96:127]
        FINX("s12")
        // ---- row B (odd): in flight: SMEM B, ds_B ----
        "s_waitcnt lgkmcnt(0)\n\t"
        SMEM_A_NEXT                            // next pair A; s15 = clamped+0x80
        EINSM_B
        B_B32_THEN_DSA                         // b32 consumes v[96:111]; reissue ds_A(next)
        B_B48                                  // b48 consumes v[112:127]; v94 += 192
        FINX("s13")
        C2_NEXT                                // c2(next) -> s[12:13], after both FINX
        "s_add_u32 s14, s14, 0x200\n\t"
        "s_cmp_lg_u32 s14, 0x10000\n\t"
        "s_cbranch_scc1 Ltop_%=\n\t"
        "s_waitcnt lgkmcnt(0)\n\t"             // drain trailing prefetches
        "v_mov_b32 %[ob], v89\n\t"
        "v_mov_b32 %[oi], v90\n\t"
        : [ob] "=v"(best), [oi] "=v"(bidx)
        : [ra] "v"(ra), [pb] "s"(pbw), [m0] "v"(m0), [lb] "v"(ldsbase)
        : "vcc", "scc",
          "s12","s13","s14","s15",
          "s16","s17","s18","s19","s20","s21","s22","s23","s24","s25","s26","s27",
          "s28","s29","s30","s31","s32","s33","s34","s35","s36","s37","s38","s39",
          "s40","s41","s42","s43","s44","s45","s46","s47","s48","s49","s50","s51",
          "s52","s53","s54","s55","s56","s57","s58","s59","s60","s61","s62","s63",
          "s64","s65","s66","s67","s68","s69","s70","s71","s72","s73","s74","s75",
          "s76","s77","s78","s79","s80","s81","s82","s83","s84","s85","s86","s87",
          "s88","s89","s90","s91","s92","s93","s94","s95",
          "v16","v17","v18","v19","v20","v21","v22","v23","v24","v25","v26","v27",
          "v28","v29","v30","v31","v32","v33","v34","v35","v36","v37","v38","v39",
          "v40","v41","v42","v43","v44","v45","v46","v47","v48","v49","v50","v51",
          "v52","v53","v54","v55","v56","v57","v58","v59","v60","v61","v62","v63",
          "v64","v65","v66","v67","v68","v69","v70","v71","v72","v73","v74","v75",
          "v76","v77","v78","v79","v80","v81","v82","v83","v84","v85","v86","v87",
          "v88","v89","v90","v91","v92","v93","v94","v96","v97","v98","v99",
          "v100","v101","v102","v103","v104","v105","v106","v107","v108","v109",
          "v110","v111","v112","v113","v114","v115","v116","v117","v118","v119",
          "v120","v121","v122","v123","v124","v125","v126","v127");

    // ---- cross-chunk combine: u64-min over {d2_bits, m}. d2 > 0 always, so
    // u64 order == (d2, then m) == reference first-occurrence semantics.
    unsigned long long key =
        ((unsigned long long)__float_as_uint(best) << 32) | (unsigned int)bidx;
    atomicMin(&keys[point], key);
}

// ---- update: unpack winner, write idx, residual update, key reset ----
// grid = QSIZE/256. Block covers 4 points x 64 dims.
__global__ __launch_bounds__(256) void rvq_update(const float* __restrict__ res_in,
                                                  float* __restrict__ res_out,
                                                  const float* __restrict__ x,
                                                  const float* __restrict__ cbk,  // (M,D)
                                                  unsigned long long* __restrict__ keys,
                                                  float* __restrict__ idx_out,
                                                  int last) {
#pragma clang fp contract(off)
    __shared__ unsigned long long sk[4];
    const int tid = threadIdx.x;
    const int e = blockIdx.x * 256 + tid;
    const int p0 = blockIdx.x * 4;
    if (tid < 4) {
        unsigned long long k = keys[p0 + tid];
        sk[tid] = k;
        keys[p0 + tid] = ~0ULL;                       // reset for next step
        idx_out[p0 + tid] = (float)(unsigned int)k;   // exact for m < 2^24
    }
    __syncthreads();
    const int pi = tid >> 6;
    const int d = tid & 63;
    const int m = (int)(unsigned int)sk[pi];
    const float r = res_in[e] - cbk[(size_t)m * DD + d];  // exact fp32 sub
    if (last) res_out[e] = x[e] - r;   // quant = fl(x - fl(res - cb)); alias-safe
    else      res_out[e] = r;
}

extern "C" void kernel_launch(void* const* d_in, const int* in_sizes, int n_in,
                              void* d_out, int out_size, void* d_ws, size_t ws_size,
                              hipStream_t stream) {
    const float* x  = (const float*)d_in[0];
    const float* cb = (const float*)d_in[1];

    float* out = (float*)d_out;
    float* quant = out;                 // QSIZE floats
    float* idx_out = out + QSIZE;       // K*NPTS floats (indices as float)

    float* res1 = (float*)d_ws;                       // NPTS*D floats (8 MB)
    unsigned long long* keys =
        (unsigned long long*)(res1 + (size_t)QSIZE);  // NPTS u64 (256 KB)
    float* pack = (float*)(keys + NPTS);              // 64 * PACKF floats (~4.25 MB)
    float* R[2] = { quant, res1 };                    // ping-pong residual

    rvq_prep<<<KK * NCHUNK, 256, 0, stream>>>(cb, pack, keys);

    for (int k = 0; k < KK; ++k) {
        const float* rin = (k == 0) ? x : R[(k - 1) & 1];
        const int last = (k == KK - 1);
        float* rout = last ? quant : R[k & 1];
        rvq_main<<<(NPTS / PPB) * NCHUNK, PPB, 0, stream>>>(
            rin,
            pack + (size_t)k * NCHUNK * PACKF,
            keys);
        rvq_update<<<QSIZE / 256, 256, 0, stream>>>(
            rin, rout, x,
            cb + (size_t)k * MM * DD,
            keys,
            idx_out + (size_t)k * NPTS,
            last);
    }
}

// Round 10
// 1281.562 us; speedup vs baseline: 1.1261x; 1.0216x over previous
//
#include <hip/hip_runtime.h>

// Residual VQ, bit-exact replication of the numpy reference's fp32 rounding.
// B=16 S=2048 D=64 K=8 M=2048.
//
// Numerics contract (verified bit-exact, absmax 0.0):
//  - r2/c2: numpy pairwise_sum 8-accumulator order, no FMA contraction
//  - cross: numpy einsum baseline-SSE order: 4 chains (d mod 4), per 16-block
//           groups at offsets {12,8,4,0}+j, blocks ascending, hsum (L0+L1)+(L2+L3)
//  - t = fl(r2 - 2*cross) via fma(-2,cross,r2); d2 = fl(t + c2)
//  - argmin: first occurrence == u64-min over key {d2_bits(hi), m(lo)} (d2>0)
//
// R16 = R15 + c2-lead fix. R15 ran 178us/step, VALU 76.6% — the asymmetric
// LDS rebalance was neutral, but R15's C2_NEXT at loop bottom (3 SALU before
// the A-top lgkmcnt(0)) exposed a full scalar round trip (~250cy, c2 lines
// are evicted by the row stream) at EVERY pair top — a self-inflicted stall
// R9 didn't have. Fix: at A-top copy s12->v15, s13->v95 (FINX consumes the
// copies), then issue c2(q+1)->s[12:13] at A-top => full-phase lead, covered
// by the B-top wait. No hazards: copies precede the reload. Everything else
// byte-identical to R15. This is the clean A/B of the asymmetric-pair theory
// vs R9 (174.9us).
//
// Structure: prep packs per-(k,chunk) [256 rows x 64f | 256 c2f] -> ONE
// scalar pointer (SGPR demand 86 <= proven-OK ceiling; >=90 fails to alloc).
//  A rows (even): d0..47 SMEM s[32:79] (3 x16), d48..63 LDS (4 b128 v[96:111])
//  B rows (odd):  d0..15 s[16:31], d16..31 s[80:95] (2 x16),
//                 d32..63 LDS (8 b128 v[96:127])
// Per pair-window (2666cy VALU): LDS 2304 (86%), scalar 1920 (72%), VMEM 0.

#define BB 16
#define SS 2048
#define DD 64
#define KK 8
#define MM 2048
#define NPTS (BB * SS)      // 32768
#define QSIZE (NPTS * DD)   // 2097152
#define NCHUNK 8
#define WPB 8               // waves per block (all same chunk)
#define PPB 512             // points per block
#define MCHUNK (MM / NCHUNK)  // 256 rows per chunk = 128 pairs
#define PACKF 16640         // floats per packed chunk block: 16384 rows + 256 c2

// ---- prep: pack rows + c2 per (k,chunk); init keys ----
// grid = 64 blocks (one per (k,chunk)) x 256 threads.
__global__ __launch_bounds__(256) void rvq_prep(const float* __restrict__ cb,
                                                float* __restrict__ pack,
                                                unsigned long long* __restrict__ keys) {
#pragma clang fp contract(off)
    const int b = blockIdx.x;          // k = b>>3, chunk = b&7
    const int tid = threadIdx.x;
    const float* src = cb + (size_t)b * 16384;   // chunk rows are contiguous
    float* dst = pack + (size_t)b * PACKF;
    // copy rows region (64KB), coalesced float4
    for (int i = tid; i < 4096; i += 256)
        *(float4*)&dst[i * 4] = *(const float4*)&src[i * 4];
    // c2 for local row tid (numpy pairwise 8-acc)
    const float* row = src + (size_t)tid * DD;
    float r[8];
#pragma unroll
    for (int j = 0; j < 8; ++j) { float v = row[j]; r[j] = v * v; }
#pragma unroll
    for (int i = 8; i < DD; i += 8) {
#pragma unroll
        for (int j = 0; j < 8; ++j) { float v = row[i + j]; float t = v * v; r[j] += t; }
    }
    dst[16384 + tid] = ((r[0] + r[1]) + (r[2] + r[3])) + ((r[4] + r[5]) + (r[6] + r[7]));
    keys[b * 512 + tid] = ~0ULL;
    keys[b * 512 + 256 + tid] = ~0ULL;
}

// r2 chain block for k-th 8-float group (bases A=16+8k, etc.)
#define R2K(A, B, C, E) \
    "v_pk_mul_f32 v[92:93], v[" A "], v[" A "]\n\t" \
    "v_pk_add_f32 v[80:81], v[80:81], v[92:93]\n\t" \
    "v_pk_mul_f32 v[92:93], v[" B "], v[" B "]\n\t" \
    "v_pk_add_f32 v[82:83], v[82:83], v[92:93]\n\t" \
    "v_pk_mul_f32 v[92:93], v[" C "], v[" C "]\n\t" \
    "v_pk_add_f32 v[84:85], v[84:85], v[92:93]\n\t" \
    "v_pk_mul_f32 v[92:93], v[" E "], v[" E "]\n\t" \
    "v_pk_add_f32 v[86:87], v[86:87], v[92:93]\n\t"

// einsum group, codebook from SGPR pairs
#define GRP(SA, SB, VA, VB) \
    "v_pk_mul_f32 v[84:85], s[" SA "], v[" VA "]\n\t" \
    "v_pk_mul_f32 v[86:87], s[" SB "], v[" VB "]\n\t" \
    "v_pk_add_f32 v[80:81], v[80:81], v[84:85]\n\t" \
    "v_pk_add_f32 v[82:83], v[82:83], v[86:87]\n\t"

// einsum group, codebook from VGPR pairs (LDS-transported)
#define GRPL(CA, CB, VA, VB) \
    "v_pk_mul_f32 v[84:85], v[" CA "], v[" VA "]\n\t" \
    "v_pk_mul_f32 v[86:87], v[" CB "], v[" VB "]\n\t" \
    "v_pk_add_f32 v[80:81], v[80:81], v[84:85]\n\t" \
    "v_pk_add_f32 v[82:83], v[82:83], v[86:87]\n\t"

// A-top: issue SMEM B (current pair row 2q+1, d0..31); temp s15
#define SMEM_B_ISSUE \
    "s_add_u32 s15, s14, 0x100\n\t" \
    "s_load_dwordx16 s[16:31], %[pb], s15\n\t" \
    "s_add_u32 s15, s15, 0x40\n\t" \
    "s_load_dwordx16 s[80:95], %[pb], s15\n\t"

// A-top (after copies + SMEM_B_ISSUE): issue c2(q+1) -> s[12:13].
// Full A-phase lead before the B-top wait; consumed at next A-top.
// offset = 0x10000 + (q+1)*8 = (s14>>6) + 0x10008, clamped to last pair.
#define C2_ISSUE \
    "s_lshr_b32 s15, s14, 6\n\t" \
    "s_add_u32 s15, s15, 0x10008\n\t" \
    "s_min_u32 s15, s15, 0x103f8\n\t" \
    "s_load_dwordx2 s[12:13], %[pb], s15\n\t"

// B-top: issue SMEM A (next pair, d0..47); temp s15
#define SMEM_A_NEXT \
    "s_add_u32 s15, s14, 0x200\n\t" \
    "s_min_u32 s15, s15, 0xfe00\n\t" \
    "s_load_dwordx16 s[32:47], %[pb], s15\n\t" \
    "s_add_u32 s15, s15, 0x40\n\t" \
    "s_load_dwordx16 s[48:63], %[pb], s15\n\t" \
    "s_add_u32 s15, s15, 0x40\n\t" \
    "s_load_dwordx16 s[64:79], %[pb], s15\n\t"

// einsum b0+b16+b32 from A SMEM buffer s[32:79] (d -> s[32+d])
#define EINSM_A \
    "v_pk_mul_f32 v[80:81], s[44:45], v[28:29]\n\t" \
    "v_pk_mul_f32 v[82:83], s[46:47], v[30:31]\n\t" \
    GRP("40:41","42:43","24:25","26:27") \
    GRP("36:37","38:39","20:21","22:23") \
    GRP("32:33","34:35","16:17","18:19") \
    GRP("60:61","62:63","44:45","46:47") \
    GRP("56:57","58:59","40:41","42:43") \
    GRP("52:53","54:55","36:37","38:39") \
    GRP("48:49","50:51","32:33","34:35") \
    GRP("76:77","78:79","60:61","62:63") \
    GRP("72:73","74:75","56:57","58:59") \
    GRP("68:69","70:71","52:53","54:55") \
    GRP("64:65","66:67","48:49","50:51")

// A b48 from LDS v[96:111] (d = 48+i -> v[96+i])
#define TAIL_A \
    GRPL("108:109","110:111","76:77","78:79") \
    GRPL("104:105","106:107","72:73","74:75") \
    GRPL("100:101","102:103","68:69","70:71") \
    GRPL("96:97","98:99","64:65","66:67")

// issue ds_B (current pair, d32..63 -> v[96:127]); pair base v94 + 64..176
#define DS_B \
    "ds_read_b128 v[96:99],   v94 offset:64\n\t" \
    "ds_read_b128 v[100:103], v94 offset:80\n\t" \
    "ds_read_b128 v[104:107], v94 offset:96\n\t" \
    "ds_read_b128 v[108:111], v94 offset:112\n\t" \
    "ds_read_b128 v[112:115], v94 offset:128\n\t" \
    "ds_read_b128 v[116:119], v94 offset:144\n\t" \
    "ds_read_b128 v[120:123], v94 offset:160\n\t" \
    "ds_read_b128 v[124:127], v94 offset:176\n\t"

// einsum b0+b16 from B SMEM buffers s[16:31] (d0..15) + s[80:95] (d16..31)
#define EINSM_B \
    "v_pk_mul_f32 v[80:81], s[28:29], v[28:29]\n\t" \
    "v_pk_mul_f32 v[82:83], s[30:31], v[30:31]\n\t" \
    GRP("24:25","26:27","24:25","26:27") \
    GRP("20:21","22:23","20:21","22:23") \
    GRP("16:17","18:19","16:17","18:19") \
    GRP("92:93","94:95","44:45","46:47") \
    GRP("88:89","90:91","40:41","42:43") \
    GRP("84:85","86:87","36:37","38:39") \
    GRP("80:81","82:83","32:33","34:35")

// B b32 from LDS v[96:111] (d = 32+i -> v[96+i]); then reissue ds_A(next pair)
// into the just-freed v[96:111] (offsets 192..240 = next pair's A region)
#define B_B32_THEN_DSA \
    GRPL("108:109","110:111","60:61","62:63") \
    GRPL("104:105","106:107","56:57","58:59") \
    GRPL("100:101","102:103","52:53","54:55") \
    GRPL("96:97","98:99","48:49","50:51") \
    "ds_read_b128 v[96:99],   v94 offset:192\n\t" \
    "ds_read_b128 v[100:103], v94 offset:208\n\t" \
    "ds_read_b128 v[104:107], v94 offset:224\n\t" \
    "ds_read_b128 v[108:111], v94 offset:240\n\t"

// B b48 from LDS v[112:127] (d = 48+i -> v[112+i]); advance pair base
#define B_B48 \
    GRPL("124:125","126:127","76:77","78:79") \
    GRPL("120:121","122:123","72:73","74:75") \
    GRPL("116:117","118:119","68:69","70:71") \
    GRPL("112:113","114:115","64:65","66:67") \
    "v_add_u32 v94, 0xc0, v94\n\t"

// hsum, d2, argmin update; C2R = register (SGPR or VGPR) holding c2
#define FINX(C2R) \
    "v_add_f32 v92, v80, v81\n\t" \
    "v_add_f32 v93, v82, v83\n\t" \
    "v_add_f32 v92, v92, v93\n\t" \
    "v_fma_f32 v92, v92, -2.0, v88\n\t" \
    "v_add_f32 v92, " C2R ", v92\n\t" \
    "v_cmp_lt_f32 vcc, v92, v89\n\t" \
    "v_cndmask_b32 v89, v89, v92, vcc\n\t" \
    "v_cndmask_b32 v90, v90, v91, vcc\n\t" \
    "v_add_u32 v91, 1, v91\n\t"

// ---- main: per-chunk argmin, atomicMin-combined ----
// grid = 512 blocks x 512 threads (8 waves). Block b: chunk = b & 7,
// point-group = b >> 3. 2 blocks/CU, 4 waves/SIMD, ~24.8KB LDS/block.
__global__ __launch_bounds__(512, 4) void rvq_main(const float* __restrict__ res_in,
                                                   const float* __restrict__ packk, // per-k pack
                                                   unsigned long long* __restrict__ keys) {
#pragma clang fp contract(off)
    const int tid = threadIdx.x;
    const int lane = tid & 63;
    const int wv = __builtin_amdgcn_readfirstlane(tid >> 6);  // 0..7
    const int ch = blockIdx.x & (NCHUNK - 1);
    const int bp = blockIdx.x >> 3;
    const int point = bp * PPB + wv * 64 + lane;

    const int m0 = ch * MCHUNK;
    const float* pbw = packk + (size_t)ch * PACKF;  // [rows 16384f | c2 256f]
    const unsigned long long ra = (unsigned long long)(res_in + (size_t)point * DD);

    // ---- stage LDS: per pair q (rows 2q,2q+1): [A d48..63 (16f)][B d32..63 (32f)]
    //      = 48 floats, 192B stride; + 1 pad pair for the tail prefetch ----
    __shared__ __align__(16) float lds_cb[128 * 48 + 48];   // 24768 B
    for (int i = tid; i < 128 * 12; i += PPB) {              // 1536 float4s
        const int q = i / 12;
        const int j = i - q * 12;
        const int row = 2 * q + (j >= 4);
        const int d = (j < 4) ? (48 + 4 * j) : (16 + 4 * j); // A: d48+4j | B: d32+4(j-4)
        *(float4*)&lds_cb[q * 48 + j * 4] = *(const float4*)(pbw + row * DD + d);
    }
    __syncthreads();
    const unsigned ldsbase = (unsigned)(unsigned long long)(void*)&lds_cb[0];

    float best;
    int bidx;
    asm volatile(
        // ---- residual: 64 floats -> v[16:79] ----
        "global_load_dwordx4 v[16:19], %[ra], off\n\t"
        "global_load_dwordx4 v[20:23], %[ra], off offset:16\n\t"
        "global_load_dwordx4 v[24:27], %[ra], off offset:32\n\t"
        "global_load_dwordx4 v[28:31], %[ra], off offset:48\n\t"
        "global_load_dwordx4 v[32:35], %[ra], off offset:64\n\t"
        "global_load_dwordx4 v[36:39], %[ra], off offset:80\n\t"
        "global_load_dwordx4 v[40:43], %[ra], off offset:96\n\t"
        "global_load_dwordx4 v[44:47], %[ra], off offset:112\n\t"
        "global_load_dwordx4 v[48:51], %[ra], off offset:128\n\t"
        "global_load_dwordx4 v[52:55], %[ra], off offset:144\n\t"
        "global_load_dwordx4 v[56:59], %[ra], off offset:160\n\t"
        "global_load_dwordx4 v[60:63], %[ra], off offset:176\n\t"
        "global_load_dwordx4 v[64:67], %[ra], off offset:192\n\t"
        "global_load_dwordx4 v[68:71], %[ra], off offset:208\n\t"
        "global_load_dwordx4 v[72:75], %[ra], off offset:224\n\t"
        "global_load_dwordx4 v[76:79], %[ra], off offset:240\n\t"
        "s_waitcnt vmcnt(0)\n\t"
        // ---- r2, numpy pairwise 8-acc order; accs in v[80:87] ----
        "v_pk_mul_f32 v[80:81], v[16:17], v[16:17]\n\t"
        "v_pk_mul_f32 v[82:83], v[18:19], v[18:19]\n\t"
        "v_pk_mul_f32 v[84:85], v[20:21], v[20:21]\n\t"
        "v_pk_mul_f32 v[86:87], v[22:23], v[22:23]\n\t"
        R2K("24:25", "26:27", "28:29", "30:31")
        R2K("32:33", "34:35", "36:37", "38:39")
        R2K("40:41", "42:43", "44:45", "46:47")
        R2K("48:49", "50:51", "52:53", "54:55")
        R2K("56:57", "58:59", "60:61", "62:63")
        R2K("64:65", "66:67", "68:69", "70:71")
        R2K("72:73", "74:75", "76:77", "78:79")
        "v_add_f32 v92, v80, v81\n\t"
        "v_add_f32 v93, v82, v83\n\t"
        "v_add_f32 v92, v92, v93\n\t"
        "v_add_f32 v93, v84, v85\n\t"
        "v_add_f32 v88, v86, v87\n\t"
        "v_add_f32 v93, v93, v88\n\t"
        "v_add_f32 v88, v92, v93\n\t"          // r2 -> v88
        // ---- init ----
        "v_mov_b32 v89, 0x7f800000\n\t"        // best = +inf
        "v_mov_b32 v90, 0\n\t"                 // bidx = 0
        "v_mov_b32 v91, %[m0]\n\t"             // current m
        "v_mov_b32 v94, %[lb]\n\t"             // LDS pair base (pair 0)
        "s_mov_b32 s14, 0\n\t"                 // pair byte base (512/pair)
        // ---- prime: SMEM A(0) + c2 pair(0) + ds_A(0) ----
        "s_load_dwordx16 s[32:47], %[pb], 0x0\n\t"
        "s_load_dwordx16 s[48:63], %[pb], 0x40\n\t"
        "s_load_dwordx16 s[64:79], %[pb], 0x80\n\t"
        "s_load_dwordx2 s[12:13], %[pb], 0x10000\n\t"
        "ds_read_b128 v[96:99],   v94\n\t"
        "ds_read_b128 v[100:103], v94 offset:16\n\t"
        "ds_read_b128 v[104:107], v94 offset:32\n\t"
        "ds_read_b128 v[108:111], v94 offset:48\n\t"
        "Ltop_%=:\n\t"
        // ---- row A (even): in flight on entry: SMEM A, c2 pair, ds_A ----
        "s_waitcnt lgkmcnt(0)\n\t"
        "v_mov_b32 v15, s12\n\t"               // c2A copy (frees s12)
        "v_mov_b32 v95, s13\n\t"               // c2B copy (frees s13)
        SMEM_B_ISSUE                           // full-phase lead for B's SMEM
        C2_ISSUE                               // c2(q+1) -> s[12:13], full-phase lead
        EINSM_A
        TAIL_A                                 // consumes v[96:111]
        DS_B                                   // issue ds_B -> v[96:127]
        FINX("v15")
        // ---- row B (odd): in flight: SMEM B, ds_B, c2(q+1) ----
        "s_waitcnt lgkmcnt(0)\n\t"
        SMEM_A_NEXT                            // next pair A rows
        EINSM_B
        B_B32_THEN_DSA                         // b32 consumes v[96:111]; reissue ds_A(next)
        B_B48                                  // b48 consumes v[112:127]; v94 += 192
        FINX("v95")
        "s_add_u32 s14, s14, 0x200\n\t"
        "s_cmp_lg_u32 s14, 0x10000\n\t"
        "s_cbranch_scc1 Ltop_%=\n\t"
        "s_waitcnt lgkmcnt(0)\n\t"             // drain trailing prefetches
        "v_mov_b32 %[ob], v89\n\t"
        "v_mov_b32 %[oi], v90\n\t"
        : [ob] "=v"(best), [oi] "=v"(bidx)
        : [ra] "v"(ra), [pb] "s"(pbw), [m0] "v"(m0), [lb] "v"(ldsbase)
        : "vcc", "scc",
          "s12","s13","s14","s15",
          "s16","s17","s18","s19","s20","s21","s22","s23","s24","s25","s26","s27",
          "s28","s29","s30","s31","s32","s33","s34","s35","s36","s37","s38","s39",
          "s40","s41","s42","s43","s44","s45","s46","s47","s48","s49","s50","s51",
          "s52","s53","s54","s55","s56","s57","s58","s59","s60","s61","s62","s63",
          "s64","s65","s66","s67","s68","s69","s70","s71","s72","s73","s74","s75",
          "s76","s77","s78","s79","s80","s81","s82","s83","s84","s85","s86","s87",
          "s88","s89","s90","s91","s92","s93","s94","s95",
          "v15",
          "v16","v17","v18","v19","v20","v21","v22","v23","v24","v25","v26","v27",
          "v28","v29","v30","v31","v32","v33","v34","v35","v36","v37","v38","v39",
          "v40","v41","v42","v43","v44","v45","v46","v47","v48","v49","v50","v51",
          "v52","v53","v54","v55","v56","v57","v58","v59","v60","v61","v62","v63",
          "v64","v65","v66","v67","v68","v69","v70","v71","v72","v73","v74","v75",
          "v76","v77","v78","v79","v80","v81","v82","v83","v84","v85","v86","v87",
          "v88","v89","v90","v91","v92","v93","v94","v95","v96","v97","v98","v99",
          "v100","v101","v102","v103","v104","v105","v106","v107","v108","v109",
          "v110","v111","v112","v113","v114","v115","v116","v117","v118","v119",
          "v120","v121","v122","v123","v124","v125","v126","v127");

    // ---- cross-chunk combine: u64-min over {d2_bits, m}. d2 > 0 always, so
    // u64 order == (d2, then m) == reference first-occurrence semantics.
    unsigned long long key =
        ((unsigned long long)__float_as_uint(best) << 32) | (unsigned int)bidx;
    atomicMin(&keys[point], key);
}

// ---- update: unpack winner, write idx, residual update, key reset ----
// grid = QSIZE/256. Block covers 4 points x 64 dims.
__global__ __launch_bounds__(256) void rvq_update(const float* __restrict__ res_in,
                                                  float* __restrict__ res_out,
                                                  const float* __restrict__ x,
                                                  const float* __restrict__ cbk,  // (M,D)
                                                  unsigned long long* __restrict__ keys,
                                                  float* __restrict__ idx_out,
                                                  int last) {
#pragma clang fp contract(off)
    __shared__ unsigned long long sk[4];
    const int tid = threadIdx.x;
    const int e = blockIdx.x * 256 + tid;
    const int p0 = blockIdx.x * 4;
    if (tid < 4) {
        unsigned long long k = keys[p0 + tid];
        sk[tid] = k;
        keys[p0 + tid] = ~0ULL;                       // reset for next step
        idx_out[p0 + tid] = (float)(unsigned int)k;   // exact for m < 2^24
    }
    __syncthreads();
    const int pi = tid >> 6;
    const int d = tid & 63;
    const int m = (int)(unsigned int)sk[pi];
    const float r = res_in[e] - cbk[(size_t)m * DD + d];  // exact fp32 sub
    if (last) res_out[e] = x[e] - r;   // quant = fl(x - fl(res - cb)); alias-safe
    else      res_out[e] = r;
}

extern "C" void kernel_launch(void* const* d_in, const int* in_sizes, int n_in,
                              void* d_out, int out_size, void* d_ws, size_t ws_size,
                              hipStream_t stream) {
    const float* x  = (const float*)d_in[0];
    const float* cb = (const float*)d_in[1];

    float* out = (float*)d_out;
    float* quant = out;                 // QSIZE floats
    float* idx_out = out + QSIZE;       // K*NPTS floats (indices as float)

    float* res1 = (float*)d_ws;                       // NPTS*D floats (8 MB)
    unsigned long long* keys =
        (unsigned long long*)(res1 + (size_t)QSIZE);  // NPTS u64 (256 KB)
    float* pack = (float*)(keys + NPTS);              // 64 * PACKF floats (~4.25 MB)
    float* R[2] = { quant, res1 };                    // ping-pong residual

    rvq_prep<<<KK * NCHUNK, 256, 0, stream>>>(cb, pack, keys);

    for (int k = 0; k < KK; ++k) {
        const float* rin = (k == 0) ? x : R[(k - 1) & 1];
        const int last = (k == KK - 1);
        float* rout = last ? quant : R[k & 1];
        rvq_main<<<(NPTS / PPB) * NCHUNK, PPB, 0, stream>>>(
            rin,
            pack + (size_t)k * NCHUNK * PACKF,
            keys);
        rvq_update<<<QSIZE / 256, 256, 0, stream>>>(
            rin, rout, x,
            cb + (size_t)k * MM * DD,
            keys,
            idx_out + (size_t)k * NPTS,
            last);
    }
}